// Round 2
// baseline (352.968 us; speedup 1.0000x reference)
//
#include <hip/hip_runtime.h>
#include <hip/hip_bf16.h>
#include <stdint.h>

typedef unsigned short u16;
typedef __bf16 bf16x8 __attribute__((ext_vector_type(8)));
typedef float f32x4 __attribute__((ext_vector_type(4)));

#define MTOT 65536

__device__ __forceinline__ u16 f2b(float f) {
    uint32_t u = __float_as_uint(f);
    u += 0x7fffu + ((u >> 16) & 1u);
    return (u16)(u >> 16);
}
__device__ __forceinline__ float b2f(u16 h) {
    return __uint_as_float(((uint32_t)h) << 16);
}

// ---------------- zero stats (replaces hipMemsetAsync) ----------------
__global__ void zero_stats(float* __restrict__ p) {
    int i = blockIdx.x * 256 + threadIdx.x;
    if (i < 3072) p[i] = 0.f;
}

// ---------------- PE table: PEC[(dy*8+dx)][n] = b1[n] + sum_lv sum_j pe_lv_j * w1[n][lv*298+j]
__global__ __launch_bounds__(512) void build_pec(const float* __restrict__ w1,
                                                 const float* __restrict__ b1,
                                                 float* __restrict__ pec) {
    __shared__ float pe[168];
    int dy = blockIdx.x >> 3, dx = blockIdx.x & 7;
    int t = threadIdx.x;
    if (t < 168) {
        int lv = t / 42, j = t - lv * 42;
        int msk = (1 << lv) - 1;
        float inv = 1.0f / (float)(1 << lv);
        float ry = (float)(2 * (dy & msk) + 1) * inv - 1.0f;
        float rx = (float)(2 * (dx & msk) + 1) * inv - 1.0f;
        float v;
        if (j == 0) v = ry;
        else if (j == 1) v = rx;
        else if (j < 12)  v = sinf(exp2f((float)(j - 2)  * (2.0f/3.0f)) * ry);
        else if (j < 22)  v = sinf(exp2f((float)(j - 12) * (2.0f/3.0f)) * rx);
        else if (j < 32)  v = cosf(exp2f((float)(j - 22) * (2.0f/3.0f)) * ry);
        else              v = cosf(exp2f((float)(j - 32) * (2.0f/3.0f)) * rx);
        pe[t] = v;
    }
    __syncthreads();
    int n = t;
    float acc = b1[n];
#pragma unroll 4
    for (int lv = 0; lv < 4; ++lv)
        for (int j = 0; j < 42; ++j)
            acc += pe[lv * 42 + j] * w1[n * 1192 + lv * 298 + j];
    pec[(size_t)blockIdx.x * 512 + n] = acc;
}

// ---------------- W1 feature-part extract: wb1f[(lv*512+n)][c] = w1[n][lv*298+42+c]
__global__ void cvt_w1f(const float* __restrict__ w1, u16* __restrict__ dst) {
    for (int i = blockIdx.x * 256 + threadIdx.x; i < 4 * 512 * 256; i += gridDim.x * 256) {
        int lv = i >> 17;
        int rem = i & 131071;
        int n = rem >> 8, c = rem & 255;
        dst[i] = f2b(w1[n * 1192 + lv * 298 + 42 + c]);
    }
}

// ---------------- flat f32 -> bf16 ----------------
__global__ void cvt_flat(const float* __restrict__ src, u16* __restrict__ dst, int total) {
    for (int i = blockIdx.x * 256 + threadIdx.x; i < total; i += gridDim.x * 256) {
        dst[i] = f2b(src[i]);
    }
}

// ---------------- transpose+convert x [B][256][plane] f32 -> A [B*plane][256] bf16
__global__ __launch_bounds__(256) void cvt_tr(const float* __restrict__ xs,
                                              u16* __restrict__ A, int shift) {
    __shared__ float sm[64][65];
    int t = threadIdx.x;
    int p0 = blockIdx.x * 64;
    int pix = t & 63, c0 = t >> 6;
    int plane = 1 << shift;
    int gp = p0 + pix;
    int b = gp >> shift;
    int l = gp & (plane - 1);
    const float* src = xs + ((size_t)b * 256) * plane + l;
    for (int cblk = 0; cblk < 4; ++cblk) {
#pragma unroll
        for (int it = 0; it < 16; ++it) {
            int c = it * 4 + c0;
            sm[pix][c] = src[(size_t)(cblk * 64 + c) * plane];
        }
        __syncthreads();
#pragma unroll
        for (int it = 0; it < 2; ++it) {
            int u = it * 256 + t;
            int ml = u >> 3, c8 = u & 7;
            const float* sr = &sm[ml][c8 * 8];
            uint4 v;
            v.x = (uint32_t)f2b(sr[0]) | ((uint32_t)f2b(sr[1]) << 16);
            v.y = (uint32_t)f2b(sr[2]) | ((uint32_t)f2b(sr[3]) << 16);
            v.z = (uint32_t)f2b(sr[4]) | ((uint32_t)f2b(sr[5]) << 16);
            v.w = (uint32_t)f2b(sr[6]) | ((uint32_t)f2b(sr[7]) << 16);
            *(uint4*)&A[(size_t)(p0 + ml) * 256 + cblk * 64 + c8 * 8] = v;
        }
        __syncthreads();
    }
}

// ---------------- GEMM: Y[m][n] = sum_k Act[m][k]*W[n][k] (+bias) (+BN stats) ----------------
// 128x128 tile, BK=64, 4 waves (2x2). grid (N/128, M/128).
__global__ __launch_bounds__(256) void gemm_bt(const u16* __restrict__ W,
                                               const u16* __restrict__ Act,
                                               const float* __restrict__ bias,
                                               u16* __restrict__ Y,
                                               float* __restrict__ stats, int N, int K) {
    __shared__ u16 As[128 * 64];
    __shared__ u16 Ws[128 * 64];
    int tid = threadIdx.x;
    int wave = tid >> 6, lane = tid & 63;
    int wm = wave >> 1, wn = wave & 1;
    int n0 = blockIdx.x * 128, m0 = blockIdx.y * 128;
    int q = lane >> 4, l16 = lane & 15;
    f32x4 acc[4][4];
#pragma unroll
    for (int i = 0; i < 4; ++i)
#pragma unroll
        for (int j = 0; j < 4; ++j) acc[i][j] = {0.f, 0.f, 0.f, 0.f};
    int lr = lane >> 3, ch = lane & 7;
    const char* actb = (const char*)Act;
    const char* wb = (const char*)W;
    size_t ldb = (size_t)K * 2;
    for (int kt = 0; kt < K; kt += 64) {
#pragma unroll
        for (int i = 0; i < 4; ++i) {
            int r = wave * 32 + i * 8 + lr;
            uint4 va = *(const uint4*)(actb + (size_t)(m0 + r) * ldb + kt * 2 + ch * 16);
            *(uint4*)&As[r * 64 + ch * 8] = va;
            uint4 vw = *(const uint4*)(wb + (size_t)(n0 + r) * ldb + kt * 2 + ch * 16);
            *(uint4*)&Ws[r * 64 + ch * 8] = vw;
        }
        __syncthreads();
#pragma unroll
        for (int kk = 0; kk < 64; kk += 32) {
            bf16x8 af[4], wf[4];
#pragma unroll
            for (int mi = 0; mi < 4; ++mi)
                af[mi] = *(const bf16x8*)&As[(wm * 64 + mi * 16 + l16) * 64 + kk + q * 8];
#pragma unroll
            for (int ni = 0; ni < 4; ++ni)
                wf[ni] = *(const bf16x8*)&Ws[(wn * 64 + ni * 16 + l16) * 64 + kk + q * 8];
#pragma unroll
            for (int mi = 0; mi < 4; ++mi)
#pragma unroll
                for (int ni = 0; ni < 4; ++ni)
                    acc[mi][ni] = __builtin_amdgcn_mfma_f32_16x16x32_bf16(af[mi], wf[ni], acc[mi][ni], 0, 0, 0);
        }
        __syncthreads();
    }
    float bv[4];
#pragma unroll
    for (int ni = 0; ni < 4; ++ni)
        bv[ni] = bias ? bias[n0 + wn * 64 + ni * 16 + l16] : 0.f;
    float s1[4] = {0.f, 0.f, 0.f, 0.f}, s2[4] = {0.f, 0.f, 0.f, 0.f};
#pragma unroll
    for (int mi = 0; mi < 4; ++mi) {
#pragma unroll
        for (int r = 0; r < 4; ++r) {
            int m = m0 + wm * 64 + mi * 16 + q * 4 + r;
#pragma unroll
            for (int ni = 0; ni < 4; ++ni) {
                float v = acc[mi][ni][r] + bv[ni];
                Y[(size_t)m * N + (n0 + wn * 64 + ni * 16 + l16)] = f2b(v);
                s1[ni] += v;
                s2[ni] += v * v;
            }
        }
    }
    if (stats) {
#pragma unroll
        for (int ni = 0; ni < 4; ++ni) {
            float a = s1[ni], bq = s2[ni];
            a += __shfl_xor(a, 16); a += __shfl_xor(a, 32);
            bq += __shfl_xor(bq, 16); bq += __shfl_xor(bq, 32);
            if (q == 0) {
                int n = n0 + wn * 64 + ni * 16 + l16;
                atomicAdd(&stats[n], a);
                atomicAdd(&stats[N + n], bq);
            }
        }
    }
}

// ---------------- fused layer-1 GEMM: Y1 = A0*W0^T + gather(G1,G2,G3) + PEC; stats ----------------
// N=512, K=256 fixed. grid (4, 512). m-tile of 128 = one (b, iy) row, ix 0..127.
__global__ __launch_bounds__(256) void gemm_f1(const u16* __restrict__ W,
                                               const u16* __restrict__ A0,
                                               const u16* __restrict__ G1,
                                               const u16* __restrict__ G2,
                                               const u16* __restrict__ G3,
                                               const float* __restrict__ pec,
                                               u16* __restrict__ Y,
                                               float* __restrict__ stats) {
    __shared__ u16 As[128 * 64];
    __shared__ u16 Ws[128 * 64];
    int tid = threadIdx.x;
    int wave = tid >> 6, lane = tid & 63;
    int wm = wave >> 1, wn = wave & 1;
    int n0 = blockIdx.x * 128, m0 = blockIdx.y * 128;
    int q = lane >> 4, l16 = lane & 15;
    f32x4 acc[4][4];
#pragma unroll
    for (int i = 0; i < 4; ++i)
#pragma unroll
        for (int j = 0; j < 4; ++j) acc[i][j] = {0.f, 0.f, 0.f, 0.f};
    int lr = lane >> 3, ch = lane & 7;
    const char* actb = (const char*)A0;
    const char* wb = (const char*)W;
    for (int kt = 0; kt < 256; kt += 64) {
#pragma unroll
        for (int i = 0; i < 4; ++i) {
            int r = wave * 32 + i * 8 + lr;
            uint4 va = *(const uint4*)(actb + (size_t)(m0 + r) * 512 + kt * 2 + ch * 16);
            *(uint4*)&As[r * 64 + ch * 8] = va;
            uint4 vw = *(const uint4*)(wb + (size_t)(n0 + r) * 512 + kt * 2 + ch * 16);
            *(uint4*)&Ws[r * 64 + ch * 8] = vw;
        }
        __syncthreads();
#pragma unroll
        for (int kk = 0; kk < 64; kk += 32) {
            bf16x8 af[4], wf[4];
#pragma unroll
            for (int mi = 0; mi < 4; ++mi)
                af[mi] = *(const bf16x8*)&As[(wm * 64 + mi * 16 + l16) * 64 + kk + q * 8];
#pragma unroll
            for (int ni = 0; ni < 4; ++ni)
                wf[ni] = *(const bf16x8*)&Ws[(wn * 64 + ni * 16 + l16) * 64 + kk + q * 8];
#pragma unroll
            for (int mi = 0; mi < 4; ++mi)
#pragma unroll
                for (int ni = 0; ni < 4; ++ni)
                    acc[mi][ni] = __builtin_amdgcn_mfma_f32_16x16x32_bf16(af[mi], wf[ni], acc[mi][ni], 0, 0, 0);
        }
        __syncthreads();
    }
    // ---- epilogue: stage gather rows in LDS (aliasing As/Ws) ----
    u16* g1s = As;                       // [64][128] 16KB
    u16* g2s = Ws;                       // [32][128] 8KB
    u16* g3s = Ws + 32 * 128;            // [16][128] 4KB
    float* pecs = (float*)(Ws + 48 * 128); // [8][128] 4KB
    int b = m0 >> 14;
    int iy = (m0 >> 7) & 127;
    {
        const u16* g1p = G1 + ((size_t)(b * 4096 + (iy >> 1) * 64)) * 512 + n0;
#pragma unroll
        for (int it = 0; it < 4; ++it) {
            int u = it * 256 + tid;
            int row = u >> 4, c8 = u & 15;
            *(uint4*)&g1s[row * 128 + c8 * 8] = *(const uint4*)&g1p[(size_t)row * 512 + c8 * 8];
        }
        const u16* g2p = G2 + ((size_t)(b * 1024 + (iy >> 2) * 32)) * 512 + n0;
#pragma unroll
        for (int it = 0; it < 2; ++it) {
            int u = it * 256 + tid;
            int row = u >> 4, c8 = u & 15;
            *(uint4*)&g2s[row * 128 + c8 * 8] = *(const uint4*)&g2p[(size_t)row * 512 + c8 * 8];
        }
        const u16* g3p = G3 + ((size_t)(b * 256 + (iy >> 3) * 16)) * 512 + n0;
        {
            int row = tid >> 4, c8 = tid & 15;
            *(uint4*)&g3s[row * 128 + c8 * 8] = *(const uint4*)&g3p[(size_t)row * 512 + c8 * 8];
        }
        const float* pp = pec + (size_t)((iy & 7) * 8) * 512 + n0;
        {
            int row = tid >> 5, c4 = tid & 31;
            *(uint4*)&pecs[row * 128 + c4 * 4] = *(const uint4*)&pp[(size_t)row * 512 + c4 * 4];
        }
    }
    __syncthreads();
    float s1[4] = {0.f, 0.f, 0.f, 0.f}, s2[4] = {0.f, 0.f, 0.f, 0.f};
#pragma unroll
    for (int mi = 0; mi < 4; ++mi) {
#pragma unroll
        for (int r = 0; r < 4; ++r) {
            int ix = wm * 64 + mi * 16 + q * 4 + r;
#pragma unroll
            for (int ni = 0; ni < 4; ++ni) {
                int nl = wn * 64 + ni * 16 + l16;
                float v = acc[mi][ni][r]
                        + b2f(g1s[(ix >> 1) * 128 + nl])
                        + b2f(g2s[(ix >> 2) * 128 + nl])
                        + b2f(g3s[(ix >> 3) * 128 + nl])
                        + pecs[(ix & 7) * 128 + nl];
                Y[(size_t)(m0 + ix) * 512 + (n0 + nl)] = f2b(v);
                s1[ni] += v;
                s2[ni] += v * v;
            }
        }
    }
#pragma unroll
    for (int ni = 0; ni < 4; ++ni) {
        float a = s1[ni], bq = s2[ni];
        a += __shfl_xor(a, 16); a += __shfl_xor(a, 32);
        bq += __shfl_xor(bq, 16); bq += __shfl_xor(bq, 32);
        if (q == 0) {
            int n = n0 + wn * 64 + ni * 16 + l16;
            atomicAdd(&stats[n], a);
            atomicAdd(&stats[512 + n], bq);
        }
    }
}

// ---------------- BN finalize: stats -> scale/shift ----------------
__global__ void finalize_bn(const float* __restrict__ stats, const float* __restrict__ g,
                            const float* __restrict__ be, float* __restrict__ bnp, int N) {
    int n = blockIdx.x * blockDim.x + threadIdx.x;
    if (n >= N) return;
    float inv = 1.0f / (float)MTOT;
    float mean = stats[n] * inv;
    float var = stats[N + n] * inv - mean * mean;
    float sc = g[n] * rsqrtf(var + 1e-5f);
    bnp[n] = sc;
    bnp[N + n] = be[n] - mean * sc;
}

// ---------------- in-place BN + ReLU on bf16 [M][N] ----------------
__global__ void bn_relu(u16* __restrict__ Y, const float* __restrict__ bnp,
                        int N, int nmask8, int total8) {
    const float* scale = bnp;
    const float* shift = bnp + N;
    for (int i = blockIdx.x * 256 + threadIdx.x; i < total8; i += gridDim.x * 256) {
        int nb = (i & nmask8) * 8;
        uint4 v = *(const uint4*)&Y[(size_t)i * 8];
        uint32_t w[4] = {v.x, v.y, v.z, v.w};
        uint32_t o[4];
#pragma unroll
        for (int p = 0; p < 4; ++p) {
            int n = nb + p * 2;
            float f0 = __uint_as_float(w[p] << 16);
            float f1 = __uint_as_float(w[p] & 0xffff0000u);
            f0 = fmaxf(f0 * scale[n] + shift[n], 0.f);
            f1 = fmaxf(f1 * scale[n + 1] + shift[n + 1], 0.f);
            o[p] = (uint32_t)f2b(f0) | ((uint32_t)f2b(f1) << 16);
        }
        *(uint4*)&Y[(size_t)i * 8] = make_uint4(o[0], o[1], o[2], o[3]);
    }
}

// ---------------- final: BN3+ReLU fused 256 -> 19 conv, writes [B][19][L] f32 ----------------
__global__ __launch_bounds__(256) void gemm4_out(const u16* __restrict__ Y3,
                                                 const float* __restrict__ w4,
                                                 const float* __restrict__ b4,
                                                 const float* __restrict__ bnp3,
                                                 float* __restrict__ out) {
    __shared__ float w4s[19 * 256];
    int t = threadIdx.x;
    for (int i = t; i < 19 * 256; i += 256) w4s[i] = w4[i];
    __syncthreads();
    int mloc = t >> 4, l16 = t & 15;
    int m = blockIdx.x * 16 + mloc;
    float sc[16], sh[16];
#pragma unroll
    for (int j = 0; j < 16; ++j) {
        sc[j] = bnp3[l16 * 16 + j];
        sh[j] = bnp3[256 + l16 * 16 + j];
    }
    const uint4* yp = (const uint4*)((const char*)Y3 + (size_t)m * 512 + l16 * 32);
    uint4 v0 = yp[0], v1 = yp[1];
    uint32_t uu[8] = {v0.x, v0.y, v0.z, v0.w, v1.x, v1.y, v1.z, v1.w};
    float y[16];
#pragma unroll
    for (int p = 0; p < 8; ++p) {
        y[p * 2]     = __uint_as_float(uu[p] << 16);
        y[p * 2 + 1] = __uint_as_float(uu[p] & 0xffff0000u);
    }
#pragma unroll
    for (int j = 0; j < 16; ++j) y[j] = fmaxf(y[j] * sc[j] + sh[j], 0.f);
    float accv[19];
#pragma unroll
    for (int c = 0; c < 19; ++c) {
        const float* wr = &w4s[c * 256 + l16 * 16];
        float s = 0.f;
#pragma unroll
        for (int j = 0; j < 16; ++j) s += y[j] * wr[j];
        accv[c] = s;
    }
#pragma unroll
    for (int c = 0; c < 19; ++c) {
        float s = accv[c];
        s += __shfl_xor(s, 8, 16);
        s += __shfl_xor(s, 4, 16);
        s += __shfl_xor(s, 2, 16);
        s += __shfl_xor(s, 1, 16);
        accv[c] = s;
    }
    if (l16 == 0) {
        int b = m >> 14, l = m & 16383;
#pragma unroll
        for (int c = 0; c < 19; ++c)
            out[((size_t)b * 19 + c) * 16384 + l] = accv[c] + b4[c];
    }
}

extern "C" void kernel_launch(void* const* d_in, const int* in_sizes, int n_in,
                              void* d_out, int out_size, void* d_ws, size_t ws_size,
                              hipStream_t stream) {
    const float* x1 = (const float*)d_in[0];
    const float* x2 = (const float*)d_in[1];
    const float* x3 = (const float*)d_in[2];
    const float* x4 = (const float*)d_in[3];
    const float* w1 = (const float*)d_in[4];
    const float* b1 = (const float*)d_in[5];
    const float* g1 = (const float*)d_in[6];
    const float* be1 = (const float*)d_in[7];
    const float* w2 = (const float*)d_in[8];
    const float* b2 = (const float*)d_in[9];
    const float* g2 = (const float*)d_in[10];
    const float* be2 = (const float*)d_in[11];
    const float* w3 = (const float*)d_in[12];
    const float* b3 = (const float*)d_in[13];
    const float* g3 = (const float*)d_in[14];
    const float* be3 = (const float*)d_in[15];
    const float* w4 = (const float*)d_in[16];
    const float* b4 = (const float*)d_in[17];

    // workspace layout (bytes) — total 135,815,168 (< typical ws_size)
    char* ws = (char*)d_ws;
    u16* A0  = (u16*)(ws + 0);            // [65536][256] bf16 (33,554,432) — reused as Y3
    u16* Y3  = (u16*)(ws + 0);
    u16* A1  = (u16*)(ws + 33554432);     // [16384][256] (8,388,608)
    u16* A2  = (u16*)(ws + 41943040);     // [4096][256]  (2,097,152)
    u16* A3  = (u16*)(ws + 44040192);     // [1024][256]  (524,288)
    u16* G1  = (u16*)(ws + 44564480);     // [16384][512] (16,777,216)
    u16* G2  = (u16*)(ws + 61341696);     // [4096][512]  (4,194,304)
    u16* G3  = (u16*)(ws + 65536000);     // [1024][512]  (1,048,576) ends 66,584,576
    u16* Y2  = (u16*)(ws + 33554432);     // [65536][256] reuses A1..G3 region (ends 67,108,864)
    u16* Y1  = (u16*)(ws + 67108864);     // [65536][512] (67,108,864) ends 134,217,728
    u16* wb1f = (u16*)(ws + 134217728);   // [4][512][256] (1,048,576)
    u16* wb2 = (u16*)(ws + 135266304);    // [256][512] (262,144)
    u16* wb3 = (u16*)(ws + 135528448);    // [256][256] (131,072)
    float* pec = (float*)(ws + 135659520);// [64][512] f32 (131,072)
    float* stats = (float*)(ws + 135790592); // 3 x (sum, sumsq) (12,288)
    float* bnp   = (float*)(ws + 135802880); // 3 x (scale, shift) (12,288)

    zero_stats<<<12, 256, 0, stream>>>(stats);
    build_pec<<<64, 512, 0, stream>>>(w1, b1, pec);
    cvt_w1f<<<512, 256, 0, stream>>>(w1, wb1f);
    cvt_flat<<<256, 256, 0, stream>>>(w2, wb2, 256 * 512);
    cvt_flat<<<128, 256, 0, stream>>>(w3, wb3, 256 * 256);

    cvt_tr<<<1024, 256, 0, stream>>>(x1, A0, 14);
    cvt_tr<<<256, 256, 0, stream>>>(x2, A1, 12);
    cvt_tr<<<64, 256, 0, stream>>>(x3, A2, 10);
    cvt_tr<<<16, 256, 0, stream>>>(x4, A3, 8);

    // low-res level GEMMs (no bias/stats)
    gemm_bt<<<dim3(4, 128), 256, 0, stream>>>(wb1f + 1 * 512 * 256, A1, nullptr, G1, nullptr, 512, 256);
    gemm_bt<<<dim3(4, 32), 256, 0, stream>>>(wb1f + 2 * 512 * 256, A2, nullptr, G2, nullptr, 512, 256);
    gemm_bt<<<dim3(4, 8), 256, 0, stream>>>(wb1f + 3 * 512 * 256, A3, nullptr, G3, nullptr, 512, 256);

    // fused layer 1
    gemm_f1<<<dim3(4, 512), 256, 0, stream>>>(wb1f, A0, G1, G2, G3, pec, Y1, stats);
    finalize_bn<<<2, 256, 0, stream>>>(stats, g1, be1, bnp, 512);
    bn_relu<<<2048, 256, 0, stream>>>(Y1, bnp, 512, 63, 65536 * 64);

    gemm_bt<<<dim3(2, 512), 256, 0, stream>>>(wb2, Y1, b2, Y2, stats + 1024, 256, 512);
    finalize_bn<<<1, 256, 0, stream>>>(stats + 1024, g2, be2, bnp + 1024, 256);
    bn_relu<<<2048, 256, 0, stream>>>(Y2, bnp + 1024, 256, 31, 65536 * 32);

    gemm_bt<<<dim3(2, 512), 256, 0, stream>>>(wb3, Y2, b3, Y3, stats + 2048, 256, 256);
    finalize_bn<<<1, 256, 0, stream>>>(stats + 2048, g3, be3, bnp + 2048, 256);

    gemm4_out<<<4096, 256, 0, stream>>>(Y3, w4, b4, bnp + 2048, (float*)d_out);
}

// Round 3
// 313.357 us; speedup vs baseline: 1.1264x; 1.1264x over previous
//
#include <hip/hip_runtime.h>
#include <hip/hip_bf16.h>
#include <stdint.h>

typedef unsigned short u16;
typedef __bf16 bf16x8 __attribute__((ext_vector_type(8)));
typedef float f32x4 __attribute__((ext_vector_type(4)));

#define MTOT 65536

__device__ __forceinline__ u16 f2b(float f) {
    uint32_t u = __float_as_uint(f);
    u += 0x7fffu + ((u >> 16) & 1u);
    return (u16)(u >> 16);
}
__device__ __forceinline__ float b2f(u16 h) {
    return __uint_as_float(((uint32_t)h) << 16);
}

__device__ __forceinline__ void gload16(const void* g, void* l) {
    __builtin_amdgcn_global_load_lds((const __attribute__((address_space(1))) void*)g,
                                     (__attribute__((address_space(3))) void*)l, 16, 0, 0);
}

// stage one 128x64 bf16 operand tile (row-major, 128B rows) via global_load_lds.
// gbase points at row 0 / k-byte 0 of the tile (already offset by m0/n0 and kt).
__device__ __forceinline__ void stage_tile(const char* gbase, size_t ldb,
                                           u16* lbuf, int wave, int lane) {
    const char* src = gbase + (size_t)(wave * 32 + (lane >> 3)) * ldb + (lane & 7) * 16;
#pragma unroll
    for (int i = 0; i < 4; ++i)
        gload16(src + (size_t)i * 8 * ldb, lbuf + (wave * 32 + i * 8) * 64);
}

__device__ __forceinline__ void compute64(const u16* As, const u16* Ws, int wm, int wn,
                                          int l16, int q, f32x4 (&acc)[4][4]) {
#pragma unroll
    for (int kk = 0; kk < 64; kk += 32) {
        bf16x8 af[4], wf[4];
#pragma unroll
        for (int mi = 0; mi < 4; ++mi)
            af[mi] = *(const bf16x8*)&As[(wm * 64 + mi * 16 + l16) * 64 + kk + q * 8];
#pragma unroll
        for (int ni = 0; ni < 4; ++ni)
            wf[ni] = *(const bf16x8*)&Ws[(wn * 64 + ni * 16 + l16) * 64 + kk + q * 8];
#pragma unroll
        for (int mi = 0; mi < 4; ++mi)
#pragma unroll
            for (int ni = 0; ni < 4; ++ni)
                acc[mi][ni] = __builtin_amdgcn_mfma_f32_16x16x32_bf16(af[mi], wf[ni], acc[mi][ni], 0, 0, 0);
    }
}

// XCD-aware bijective swizzle (nwg % 8 == 0 required)
__device__ __forceinline__ int xcd_swz(int flat, int nwg) {
    int chunk = nwg >> 3;
    return (flat & 7) * chunk + (flat >> 3);
}

// ---------------- zero stats ----------------
__global__ void zero_stats(float* __restrict__ p) {
    int i = blockIdx.x * 256 + threadIdx.x;
    if (i < 3072) p[i] = 0.f;
}

// ---------------- PE table: PEC[(dy*8+dx)][n] ----------------
__global__ __launch_bounds__(512) void build_pec(const float* __restrict__ w1,
                                                 const float* __restrict__ b1,
                                                 float* __restrict__ pec) {
    __shared__ float pe[168];
    int dy = blockIdx.x >> 3, dx = blockIdx.x & 7;
    int t = threadIdx.x;
    if (t < 168) {
        int lv = t / 42, j = t - lv * 42;
        int msk = (1 << lv) - 1;
        float inv = 1.0f / (float)(1 << lv);
        float ry = (float)(2 * (dy & msk) + 1) * inv - 1.0f;
        float rx = (float)(2 * (dx & msk) + 1) * inv - 1.0f;
        float v;
        if (j == 0) v = ry;
        else if (j == 1) v = rx;
        else if (j < 12)  v = sinf(exp2f((float)(j - 2)  * (2.0f/3.0f)) * ry);
        else if (j < 22)  v = sinf(exp2f((float)(j - 12) * (2.0f/3.0f)) * rx);
        else if (j < 32)  v = cosf(exp2f((float)(j - 22) * (2.0f/3.0f)) * ry);
        else              v = cosf(exp2f((float)(j - 32) * (2.0f/3.0f)) * rx);
        pe[t] = v;
    }
    __syncthreads();
    int n = t;
    float acc = b1[n];
#pragma unroll 4
    for (int lv = 0; lv < 4; ++lv)
        for (int j = 0; j < 42; ++j)
            acc += pe[lv * 42 + j] * w1[n * 1192 + lv * 298 + j];
    pec[(size_t)blockIdx.x * 512 + n] = acc;
}

// ---------------- W1 feature-part extract ----------------
__global__ void cvt_w1f(const float* __restrict__ w1, u16* __restrict__ dst) {
    for (int i = blockIdx.x * 256 + threadIdx.x; i < 4 * 512 * 256; i += gridDim.x * 256) {
        int lv = i >> 17;
        int rem = i & 131071;
        int n = rem >> 8, c = rem & 255;
        dst[i] = f2b(w1[n * 1192 + lv * 298 + 42 + c]);
    }
}

// ---------------- flat f32 -> bf16 ----------------
__global__ void cvt_flat(const float* __restrict__ src, u16* __restrict__ dst, int total) {
    for (int i = blockIdx.x * 256 + threadIdx.x; i < total; i += gridDim.x * 256)
        dst[i] = f2b(src[i]);
}

// ---------------- transpose+convert x [B][256][plane] f32 -> A [B*plane][256] bf16
__global__ __launch_bounds__(256) void cvt_tr(const float* __restrict__ xs,
                                              u16* __restrict__ A, int shift) {
    __shared__ float sm[64][65];
    int t = threadIdx.x;
    int p0 = blockIdx.x * 64;
    int pix = t & 63, c0 = t >> 6;
    int plane = 1 << shift;
    int gp = p0 + pix;
    int b = gp >> shift;
    int l = gp & (plane - 1);
    const float* src = xs + ((size_t)b * 256) * plane + l;
    for (int cblk = 0; cblk < 4; ++cblk) {
#pragma unroll
        for (int it = 0; it < 16; ++it) {
            int c = it * 4 + c0;
            sm[pix][c] = src[(size_t)(cblk * 64 + c) * plane];
        }
        __syncthreads();
#pragma unroll
        for (int it = 0; it < 2; ++it) {
            int u = it * 256 + t;
            int ml = u >> 3, c8 = u & 7;
            const float* sr = &sm[ml][c8 * 8];
            uint4 v;
            v.x = (uint32_t)f2b(sr[0]) | ((uint32_t)f2b(sr[1]) << 16);
            v.y = (uint32_t)f2b(sr[2]) | ((uint32_t)f2b(sr[3]) << 16);
            v.z = (uint32_t)f2b(sr[4]) | ((uint32_t)f2b(sr[5]) << 16);
            v.w = (uint32_t)f2b(sr[6]) | ((uint32_t)f2b(sr[7]) << 16);
            *(uint4*)&A[(size_t)(p0 + ml) * 256 + cblk * 64 + c8 * 8] = v;
        }
        __syncthreads();
    }
}

// ---------------- pipelined GEMM: Y[m][n] = sum_k Act[m][k]*W[n][k] (+bias)(+stats) ----------------
// 128x128 tile, BK=64, dbuf LDS + global_load_lds. grid (N/128, M/128).
__global__ __launch_bounds__(256) void gemm_bt(const u16* __restrict__ W,
                                               const u16* __restrict__ Act,
                                               const float* __restrict__ bias,
                                               u16* __restrict__ Y,
                                               float* __restrict__ stats, int N, int K) {
    __shared__ u16 As[2][8192];
    __shared__ u16 Ws[2][8192];
    int tid = threadIdx.x;
    int wave = tid >> 6, lane = tid & 63;
    int wm = wave >> 1, wn = wave & 1;
    int nwg = gridDim.x * gridDim.y;
    int swz = xcd_swz(blockIdx.y * gridDim.x + blockIdx.x, nwg);
    int n0 = (swz % gridDim.x) * 128, m0 = (swz / gridDim.x) * 128;
    int q = lane >> 4, l16 = lane & 15;
    f32x4 acc[4][4];
#pragma unroll
    for (int i = 0; i < 4; ++i)
#pragma unroll
        for (int j = 0; j < 4; ++j) acc[i][j] = {0.f, 0.f, 0.f, 0.f};
    const char* actb = (const char*)Act + (size_t)m0 * K * 2;
    const char* wb = (const char*)W + (size_t)n0 * K * 2;
    size_t ldb = (size_t)K * 2;
    stage_tile(actb, ldb, As[0], wave, lane);
    stage_tile(wb, ldb, Ws[0], wave, lane);
    __syncthreads();
    int cur = 0;
    for (int kt = 64; kt < K; kt += 64) {
        stage_tile(actb + kt * 2, ldb, As[cur ^ 1], wave, lane);
        stage_tile(wb + kt * 2, ldb, Ws[cur ^ 1], wave, lane);
        compute64(As[cur], Ws[cur], wm, wn, l16, q, acc);
        __syncthreads();
        cur ^= 1;
    }
    compute64(As[cur], Ws[cur], wm, wn, l16, q, acc);

    float bv[4];
#pragma unroll
    for (int ni = 0; ni < 4; ++ni)
        bv[ni] = bias ? bias[n0 + wn * 64 + ni * 16 + l16] : 0.f;
    float s1[4] = {0.f, 0.f, 0.f, 0.f}, s2[4] = {0.f, 0.f, 0.f, 0.f};
#pragma unroll
    for (int mi = 0; mi < 4; ++mi) {
#pragma unroll
        for (int r = 0; r < 4; ++r) {
            int m = m0 + wm * 64 + mi * 16 + q * 4 + r;
#pragma unroll
            for (int ni = 0; ni < 4; ++ni) {
                float v = acc[mi][ni][r] + bv[ni];
                Y[(size_t)m * N + (n0 + wn * 64 + ni * 16 + l16)] = f2b(v);
                s1[ni] += v;
                s2[ni] += v * v;
            }
        }
    }
    if (stats) {
#pragma unroll
        for (int ni = 0; ni < 4; ++ni) {
            float a = s1[ni], bq = s2[ni];
            a += __shfl_xor(a, 16); a += __shfl_xor(a, 32);
            bq += __shfl_xor(bq, 16); bq += __shfl_xor(bq, 32);
            if (q == 0) {
                int n = n0 + wn * 64 + ni * 16 + l16;
                atomicAdd(&stats[n], a);
                atomicAdd(&stats[N + n], bq);
            }
        }
    }
}

// ---------------- merged low-res level GEMMs: G_lv = A_lv * W_lv^T ----------------
// grid (4, 168): y<128 -> lv1 (16384 rows), y<160 -> lv2 (4096), else lv3 (1024)
__global__ __launch_bounds__(256) void gemm_levels(const u16* __restrict__ wb1f,
                                                   const u16* __restrict__ A1,
                                                   const u16* __restrict__ A2,
                                                   const u16* __restrict__ A3,
                                                   u16* __restrict__ G1,
                                                   u16* __restrict__ G2,
                                                   u16* __restrict__ G3) {
    __shared__ u16 As[2][8192];
    __shared__ u16 Ws[2][8192];
    int tid = threadIdx.x;
    int wave = tid >> 6, lane = tid & 63;
    int wm = wave >> 1, wn = wave & 1;
    int swz = xcd_swz(blockIdx.y * 4 + blockIdx.x, 672);
    int bx = swz & 3, by = swz >> 2;
    const u16* A; u16* G; const u16* W;
    int mt;
    if (by < 128)      { A = A1; G = G1; W = wb1f + 1 * 131072; mt = by; }
    else if (by < 160) { A = A2; G = G2; W = wb1f + 2 * 131072; mt = by - 128; }
    else               { A = A3; G = G3; W = wb1f + 3 * 131072; mt = by - 160; }
    int n0 = bx * 128, m0 = mt * 128;
    int q = lane >> 4, l16 = lane & 15;
    f32x4 acc[4][4];
#pragma unroll
    for (int i = 0; i < 4; ++i)
#pragma unroll
        for (int j = 0; j < 4; ++j) acc[i][j] = {0.f, 0.f, 0.f, 0.f};
    const char* actb = (const char*)A + (size_t)m0 * 512;
    const char* wb = (const char*)W + (size_t)n0 * 512;
    stage_tile(actb, 512, As[0], wave, lane);
    stage_tile(wb, 512, Ws[0], wave, lane);
    __syncthreads();
    int cur = 0;
#pragma unroll
    for (int kt = 0; kt < 4; ++kt) {
        if (kt < 3) {
            stage_tile(actb + (kt + 1) * 128, 512, As[cur ^ 1], wave, lane);
            stage_tile(wb + (kt + 1) * 128, 512, Ws[cur ^ 1], wave, lane);
        }
        compute64(As[cur], Ws[cur], wm, wn, l16, q, acc);
        __syncthreads();
        cur ^= 1;
    }
#pragma unroll
    for (int mi = 0; mi < 4; ++mi)
#pragma unroll
        for (int r = 0; r < 4; ++r) {
            int m = m0 + wm * 64 + mi * 16 + q * 4 + r;
#pragma unroll
            for (int ni = 0; ni < 4; ++ni)
                G[(size_t)m * 512 + (n0 + wn * 64 + ni * 16 + l16)] = f2b(acc[mi][ni][r]);
        }
}

// ---------------- fused layer-1 GEMM + gathers + PEC + stats ----------------
// grid (4, 512). m-tile of 128 = one (b, iy) row, ix 0..127. K=256.
__global__ __launch_bounds__(256) void gemm_f1(const u16* __restrict__ W,
                                               const u16* __restrict__ A0,
                                               const u16* __restrict__ G1,
                                               const u16* __restrict__ G2,
                                               const u16* __restrict__ G3,
                                               const float* __restrict__ pec,
                                               u16* __restrict__ Y,
                                               float* __restrict__ stats) {
    __shared__ u16 As[2][8192];
    __shared__ u16 Ws[2][8192];
    int tid = threadIdx.x;
    int wave = tid >> 6, lane = tid & 63;
    int wm = wave >> 1, wn = wave & 1;
    int swz = xcd_swz(blockIdx.y * 4 + blockIdx.x, 2048);
    int n0 = (swz & 3) * 128, m0 = (swz >> 2) * 128;
    int q = lane >> 4, l16 = lane & 15;
    f32x4 acc[4][4];
#pragma unroll
    for (int i = 0; i < 4; ++i)
#pragma unroll
        for (int j = 0; j < 4; ++j) acc[i][j] = {0.f, 0.f, 0.f, 0.f};
    const char* actb = (const char*)A0 + (size_t)m0 * 512;
    const char* wb = (const char*)W + (size_t)n0 * 512;
    stage_tile(actb, 512, As[0], wave, lane);
    stage_tile(wb, 512, Ws[0], wave, lane);
    __syncthreads();
    int cur = 0;
#pragma unroll
    for (int kt = 0; kt < 4; ++kt) {
        if (kt < 3) {
            stage_tile(actb + (kt + 1) * 128, 512, As[cur ^ 1], wave, lane);
            stage_tile(wb + (kt + 1) * 128, 512, Ws[cur ^ 1], wave, lane);
        }
        compute64(As[cur], Ws[cur], wm, wn, l16, q, acc);
        __syncthreads();
        cur ^= 1;
    }
    // ---- epilogue: stage gather rows in LDS (reuses buffers; barrier above protects) ----
    u16* g1s = As[0];                       // [64][128] 16KB
    u16* g2s = Ws[0];                       // [32][128] 8KB
    u16* g3s = Ws[0] + 32 * 128;            // [16][128] 4KB
    float* pecs = (float*)(Ws[0] + 48 * 128); // [8][128] 4KB
    int b = m0 >> 14;
    int iy = (m0 >> 7) & 127;
    {
        const u16* g1p = G1 + ((size_t)(b * 4096 + (iy >> 1) * 64)) * 512 + n0;
#pragma unroll
        for (int it = 0; it < 4; ++it) {
            int u = it * 256 + tid;
            int row = u >> 4, c8 = u & 15;
            *(uint4*)&g1s[row * 128 + c8 * 8] = *(const uint4*)&g1p[(size_t)row * 512 + c8 * 8];
        }
        const u16* g2p = G2 + ((size_t)(b * 1024 + (iy >> 2) * 32)) * 512 + n0;
#pragma unroll
        for (int it = 0; it < 2; ++it) {
            int u = it * 256 + tid;
            int row = u >> 4, c8 = u & 15;
            *(uint4*)&g2s[row * 128 + c8 * 8] = *(const uint4*)&g2p[(size_t)row * 512 + c8 * 8];
        }
        const u16* g3p = G3 + ((size_t)(b * 256 + (iy >> 3) * 16)) * 512 + n0;
        {
            int row = tid >> 4, c8 = tid & 15;
            *(uint4*)&g3s[row * 128 + c8 * 8] = *(const uint4*)&g3p[(size_t)row * 512 + c8 * 8];
        }
        const float* pp = pec + (size_t)((iy & 7) * 8) * 512 + n0;
        {
            int row = tid >> 5, c4 = tid & 31;
            *(uint4*)&pecs[row * 128 + c4 * 4] = *(const uint4*)&pp[(size_t)row * 512 + c4 * 4];
        }
    }
    __syncthreads();
    float s1[4] = {0.f, 0.f, 0.f, 0.f}, s2[4] = {0.f, 0.f, 0.f, 0.f};
#pragma unroll
    for (int mi = 0; mi < 4; ++mi) {
#pragma unroll
        for (int r = 0; r < 4; ++r) {
            int ix = wm * 64 + mi * 16 + q * 4 + r;
#pragma unroll
            for (int ni = 0; ni < 4; ++ni) {
                int nl = wn * 64 + ni * 16 + l16;
                float v = acc[mi][ni][r]
                        + b2f(g1s[(ix >> 1) * 128 + nl])
                        + b2f(g2s[(ix >> 2) * 128 + nl])
                        + b2f(g3s[(ix >> 3) * 128 + nl])
                        + pecs[(ix & 7) * 128 + nl];
                Y[(size_t)(m0 + ix) * 512 + (n0 + nl)] = f2b(v);
                s1[ni] += v;
                s2[ni] += v * v;
            }
        }
    }
#pragma unroll
    for (int ni = 0; ni < 4; ++ni) {
        float a = s1[ni], bq = s2[ni];
        a += __shfl_xor(a, 16); a += __shfl_xor(a, 32);
        bq += __shfl_xor(bq, 16); bq += __shfl_xor(bq, 32);
        if (q == 0) {
            int n = n0 + wn * 64 + ni * 16 + l16;
            atomicAdd(&stats[n], a);
            atomicAdd(&stats[512 + n], bq);
        }
    }
}

// ---------------- BN finalize ----------------
__global__ void finalize_bn(const float* __restrict__ stats, const float* __restrict__ g,
                            const float* __restrict__ be, float* __restrict__ bnp, int N) {
    int n = blockIdx.x * blockDim.x + threadIdx.x;
    if (n >= N) return;
    float inv = 1.0f / (float)MTOT;
    float mean = stats[n] * inv;
    float var = stats[N + n] * inv - mean * mean;
    float sc = g[n] * rsqrtf(var + 1e-5f);
    bnp[n] = sc;
    bnp[N + n] = be[n] - mean * sc;
}

// ---------------- in-place BN + ReLU on bf16 [M][N] ----------------
__global__ void bn_relu(u16* __restrict__ Y, const float* __restrict__ bnp,
                        int N, int nmask8, int total8) {
    const float* scale = bnp;
    const float* shift = bnp + N;
    for (int i = blockIdx.x * 256 + threadIdx.x; i < total8; i += gridDim.x * 256) {
        int nb = (i & nmask8) * 8;
        uint4 v = *(const uint4*)&Y[(size_t)i * 8];
        uint32_t w[4] = {v.x, v.y, v.z, v.w};
        uint32_t o[4];
#pragma unroll
        for (int p = 0; p < 4; ++p) {
            int n = nb + p * 2;
            float f0 = __uint_as_float(w[p] << 16);
            float f1 = __uint_as_float(w[p] & 0xffff0000u);
            f0 = fmaxf(f0 * scale[n] + shift[n], 0.f);
            f1 = fmaxf(f1 * scale[n + 1] + shift[n + 1], 0.f);
            o[p] = (uint32_t)f2b(f0) | ((uint32_t)f2b(f1) << 16);
        }
        *(uint4*)&Y[(size_t)i * 8] = make_uint4(o[0], o[1], o[2], o[3]);
    }
}

// ---------------- final: BN3+ReLU fused 256 -> 19 conv ----------------
__global__ __launch_bounds__(256) void gemm4_out(const u16* __restrict__ Y3,
                                                 const float* __restrict__ w4,
                                                 const float* __restrict__ b4,
                                                 const float* __restrict__ bnp3,
                                                 float* __restrict__ out) {
    __shared__ float w4s[19 * 256];
    int t = threadIdx.x;
    for (int i = t; i < 19 * 256; i += 256) w4s[i] = w4[i];
    __syncthreads();
    int mloc = t >> 4, l16 = t & 15;
    int m = blockIdx.x * 16 + mloc;
    float sc[16], sh[16];
#pragma unroll
    for (int j = 0; j < 16; ++j) {
        sc[j] = bnp3[l16 * 16 + j];
        sh[j] = bnp3[256 + l16 * 16 + j];
    }
    const uint4* yp = (const uint4*)((const char*)Y3 + (size_t)m * 512 + l16 * 32);
    uint4 v0 = yp[0], v1 = yp[1];
    uint32_t uu[8] = {v0.x, v0.y, v0.z, v0.w, v1.x, v1.y, v1.z, v1.w};
    float y[16];
#pragma unroll
    for (int p = 0; p < 8; ++p) {
        y[p * 2]     = __uint_as_float(uu[p] << 16);
        y[p * 2 + 1] = __uint_as_float(uu[p] & 0xffff0000u);
    }
#pragma unroll
    for (int j = 0; j < 16; ++j) y[j] = fmaxf(y[j] * sc[j] + sh[j], 0.f);
    float accv[19];
#pragma unroll
    for (int c = 0; c < 19; ++c) {
        const float* wr = &w4s[c * 256 + l16 * 16];
        float s = 0.f;
#pragma unroll
        for (int j = 0; j < 16; ++j) s += y[j] * wr[j];
        accv[c] = s;
    }
#pragma unroll
    for (int c = 0; c < 19; ++c) {
        float s = accv[c];
        s += __shfl_xor(s, 8, 16);
        s += __shfl_xor(s, 4, 16);
        s += __shfl_xor(s, 2, 16);
        s += __shfl_xor(s, 1, 16);
        accv[c] = s;
    }
    if (l16 == 0) {
        int b = m >> 14, l = m & 16383;
#pragma unroll
        for (int c = 0; c < 19; ++c)
            out[((size_t)b * 19 + c) * 16384 + l] = accv[c] + b4[c];
    }
}

extern "C" void kernel_launch(void* const* d_in, const int* in_sizes, int n_in,
                              void* d_out, int out_size, void* d_ws, size_t ws_size,
                              hipStream_t stream) {
    const float* x1 = (const float*)d_in[0];
    const float* x2 = (const float*)d_in[1];
    const float* x3 = (const float*)d_in[2];
    const float* x4 = (const float*)d_in[3];
    const float* w1 = (const float*)d_in[4];
    const float* b1 = (const float*)d_in[5];
    const float* g1 = (const float*)d_in[6];
    const float* be1 = (const float*)d_in[7];
    const float* w2 = (const float*)d_in[8];
    const float* b2 = (const float*)d_in[9];
    const float* g2 = (const float*)d_in[10];
    const float* be2 = (const float*)d_in[11];
    const float* w3 = (const float*)d_in[12];
    const float* b3 = (const float*)d_in[13];
    const float* g3 = (const float*)d_in[14];
    const float* be3 = (const float*)d_in[15];
    const float* w4 = (const float*)d_in[16];
    const float* b4 = (const float*)d_in[17];

    char* ws = (char*)d_ws;
    u16* A0  = (u16*)(ws + 0);            // [65536][256] — reused as Y3
    u16* Y3  = (u16*)(ws + 0);
    u16* A1  = (u16*)(ws + 33554432);     // [16384][256]
    u16* A2  = (u16*)(ws + 41943040);     // [4096][256]
    u16* A3  = (u16*)(ws + 44040192);     // [1024][256]
    u16* G1  = (u16*)(ws + 44564480);     // [16384][512]
    u16* G2  = (u16*)(ws + 61341696);     // [4096][512]
    u16* G3  = (u16*)(ws + 65536000);     // [1024][512]
    u16* Y2  = (u16*)(ws + 33554432);     // [65536][256] reuses A1..G3 region
    u16* Y1  = (u16*)(ws + 67108864);     // [65536][512]
    u16* wb1f = (u16*)(ws + 134217728);   // [4][512][256]
    u16* wb2 = (u16*)(ws + 135266304);    // [256][512]
    u16* wb3 = (u16*)(ws + 135528448);    // [256][256]
    float* pec = (float*)(ws + 135659520);// [64][512] f32
    float* stats = (float*)(ws + 135790592);
    float* bnp   = (float*)(ws + 135802880);

    zero_stats<<<12, 256, 0, stream>>>(stats);
    build_pec<<<64, 512, 0, stream>>>(w1, b1, pec);
    cvt_w1f<<<512, 256, 0, stream>>>(w1, wb1f);
    cvt_flat<<<256, 256, 0, stream>>>(w2, wb2, 256 * 512);
    cvt_flat<<<128, 256, 0, stream>>>(w3, wb3, 256 * 256);

    cvt_tr<<<256, 256, 0, stream>>>(x2, A1, 12);
    cvt_tr<<<64, 256, 0, stream>>>(x3, A2, 10);
    cvt_tr<<<16, 256, 0, stream>>>(x4, A3, 8);
    gemm_levels<<<dim3(4, 168), 256, 0, stream>>>(wb1f, A1, A2, A3, G1, G2, G3);

    cvt_tr<<<1024, 256, 0, stream>>>(x1, A0, 14);
    gemm_f1<<<dim3(4, 512), 256, 0, stream>>>(wb1f, A0, G1, G2, G3, pec, Y1, stats);
    finalize_bn<<<2, 256, 0, stream>>>(stats, g1, be1, bnp, 512);
    bn_relu<<<2048, 256, 0, stream>>>(Y1, bnp, 512, 63, 65536 * 64);

    gemm_bt<<<dim3(2, 512), 256, 0, stream>>>(wb2, Y1, b2, Y2, stats + 1024, 256, 512);
    finalize_bn<<<1, 256, 0, stream>>>(stats + 1024, g2, be2, bnp + 1024, 256);
    bn_relu<<<2048, 256, 0, stream>>>(Y2, bnp + 1024, 256, 31, 65536 * 32);

    gemm_bt<<<dim3(2, 512), 256, 0, stream>>>(wb3, Y2, b3, Y3, stats + 2048, 256, 256);
    finalize_bn<<<1, 256, 0, stream>>>(stats + 2048, g3, be3, bnp + 2048, 256);

    gemm4_out<<<4096, 256, 0, stream>>>(Y3, w4, b4, bnp + 2048, (float*)d_out);
}